// Round 5
// baseline (1060.385 us; speedup 1.0000x reference)
//
#include <hip/hip_runtime.h>

// VecLeadingZeroDetector108: X [n_rows, 108] float32 bits (exact 0.0/1.0),
// out [n_rows, 7] float32 = binary (MSB-first) index of first set bit, or
// 108 = 1101100b if the row is all zero.
//
// Strategy v5: speculative 2-line head + one-shot tail (max ONE dependent
// memory boundary, vs v4's ~7-deep per-wave round chain).
//  - Per row, stream base = enclosing 128B-aligned line: off = (108*row) mod
//    32 leading floats masked off. base is 128B-aligned (X is 256B-aligned,
//    offset 4*(108r-off) = 128k bytes).
//  - Phase A (unconditional): 16 independent uint4 loads = lines 0,1 =
//    elements 0..63 (covers >= 36 row bits). Resolves ~78% of rows with
//    stream-like issue efficiency. 64-bit first-set mask via bit 23
//    (1.0f = 0x3F800000), low `off` bits cleared.
//  - Phase B (lane-predicated, ~22% of rows): read the ENTIRE rest of the
//    row (lines 2..4, uint4 q=16..33 clipped to off+108 elements — the row
//    stream length is a multiple of 4, so uint4s are fully in or fully out)
//    in one independent batch. No further dependent rounds; covers the
//    all-zero -> 108 case naturally.
//  - Output: 7 dword stores/row, dense across the wave.

#define LZD_NBITS 108
#define LZD_NOUT 7

static __device__ __forceinline__ unsigned nib(uint4 w) {
    // 4-bit mask: bit j set iff element j == 1.0f (bit 23 of the f32 pattern)
    return (w.x >> 23 & 1u) | (w.y >> 22 & 2u) |
           (w.z >> 21 & 4u) | (w.w >> 20 & 8u);
}

__global__ __launch_bounds__(256) void lzd108_kernel(const float* __restrict__ X,
                                                     float* __restrict__ out,
                                                     int n_rows) {
    const int r = blockIdx.x * blockDim.x + threadIdx.x;
    if (r >= n_rows) return;

    const unsigned off = (108u * (unsigned)r) & 31u;  // multiple of 4, 0..28
    const uint4* __restrict__ P =
        reinterpret_cast<const uint4*>(X + (size_t)r * 108u - off);

    // ---- Phase A: lines 0,1 (stream elements 0..63), all loads up front ----
    uint4 a[16];
    #pragma unroll
    for (int q = 0; q < 16; ++q) a[q] = P[q];

    unsigned long long mA = 0ull;
    #pragma unroll
    for (int q = 0; q < 16; ++q)
        mA |= (unsigned long long)nib(a[q]) << (4 * q);
    mA &= (~0ull) << off;  // elements 0..63 are all real row bits (108 > 64)

    int epos;  // first-set stream-element index, or -1 if row all zero
    if (mA) {
        epos = __builtin_ctzll(mA);
    } else {
        // ---- Phase B: the whole rest of the row in one batch ----
        // valid uint4 q iff 4q+4 <= off+108  <=>  off >= 4q-104
        unsigned long long mB = 0ull;  // elements 64..127  (q = 16..31)
        unsigned mC = 0u;              // elements 128..135 (q = 32..33)
        #pragma unroll
        for (int q = 16; q <= 26; ++q) {  // always valid (4q+4 <= 108)
            mB |= (unsigned long long)nib(P[q]) << (4 * (q - 16));
        }
        #pragma unroll
        for (int q = 27; q <= 31; ++q) {
            if (off >= 4u * (unsigned)q - 104u)
                mB |= (unsigned long long)nib(P[q]) << (4 * (q - 16));
        }
        #pragma unroll
        for (int q = 32; q <= 33; ++q) {
            if (off >= 4u * (unsigned)q - 104u)
                mC |= nib(P[q]) << (4 * (q - 32));
        }
        if (mB)       epos = 64 + __builtin_ctzll(mB);
        else if (mC)  epos = 128 + __builtin_ctz(mC);
        else          epos = -1;
    }

    const int idx = (epos < 0) ? LZD_NBITS : (epos - (int)off);

    float* o = out + (size_t)r * LZD_NOUT;
    o[0] = (float)((idx >> 6) & 1);
    o[1] = (float)((idx >> 5) & 1);
    o[2] = (float)((idx >> 4) & 1);
    o[3] = (float)((idx >> 3) & 1);
    o[4] = (float)((idx >> 2) & 1);
    o[5] = (float)((idx >> 1) & 1);
    o[6] = (float)(idx & 1);
}

extern "C" void kernel_launch(void* const* d_in, const int* in_sizes, int n_in,
                              void* d_out, int out_size, void* d_ws, size_t ws_size,
                              hipStream_t stream) {
    const float* X = (const float*)d_in[0];
    float* out = (float*)d_out;
    int n_rows = in_sizes[0] / LZD_NBITS;
    int block = 256;
    int grid = (n_rows + block - 1) / block;
    lzd108_kernel<<<grid, block, 0, stream>>>(X, out, n_rows);
}